// Round 9
// baseline (80.488 us; speedup 1.0000x reference)
//
#include <hip/hip_runtime.h>
#include <hip/hip_bf16.h>
#include <stdint.h>

#define NN 8192
#define DD 128

#define NB 512             // buckets keyed by d >> 4 (16 target rows each)
#define CHUNK 4096         // edges per partition chunk
#define SEGC 32            // per-(chunk,bucket) segment capacity (mean 8)
#define PCAP 64            // per-bucket candidate capacity (mean ~4)

typedef __bf16 bf16x8 __attribute__((ext_vector_type(8)));
typedef float  f32x4  __attribute__((ext_vector_type(4)));

__device__ inline bf16x8 ld_bf16x8(const float* p) {
    float4 u0 = *(const float4*)p;
    float4 u1 = *(const float4*)(p + 4);
    bf16x8 r;
    r[0] = (__bf16)u0.x; r[1] = (__bf16)u0.y; r[2] = (__bf16)u0.z; r[3] = (__bf16)u0.w;
    r[4] = (__bf16)u1.x; r[5] = (__bf16)u1.y; r[6] = (__bf16)u1.z; r[7] = (__bf16)u1.w;
    return r;
}

// split fp32x8 into bf16 hi + lo residual (3-term MFMA ~ fp32 accuracy)
__device__ inline void ld_split(const float* p, bf16x8& h, bf16x8& l) {
    float4 u0 = *(const float4*)p;
    float4 u1 = *(const float4*)(p + 4);
    float v[8] = {u0.x, u0.y, u0.z, u0.w, u1.x, u1.y, u1.z, u1.w};
#pragma unroll
    for (int i = 0; i < 8; ++i) {
        __bf16 hh = (__bf16)v[i];
        h[i] = hh;
        l[i] = (__bf16)(v[i] - (float)hh);
    }
}

// ---- K1: M-gemm(fp32) + SORTLESS d-keyed partition -------------------------
// blocks: [0,64) M-gemm (+c2 init) | [64, 64+npart) partition (no scan/stage)
__global__ __launch_bounds__(256) void k1_prep(
    const int* __restrict__ ei1, int e1,
    const int* __restrict__ ei2, int e2,
    const int* __restrict__ mask, int em,
    const float* __restrict__ Wq, const float* __restrict__ Wk,
    float* __restrict__ M, int* __restrict__ c2g,
    uint32_t* __restrict__ segM, uint32_t* __restrict__ seg1,
    uint32_t* __restrict__ seg2, int* __restrict__ counts,
    int nbm, int nb1, int nb2) {
    int bid = blockIdx.x;
    int t = threadIdx.x;

    if (bid < 64) {
        if (bid == 0 && t == 0) *c2g = 0;
        int c = bid * 2 + (t >> 7);
        int e = t & 127;
        float acc = 0.f;
#pragma unroll 8
        for (int a = 0; a < DD; ++a)
            acc += Wq[a * DD + c] * Wk[a * DD + e];
        M[c * DD + e] = acc;
        return;
    }
    __shared__ int cur[NB];
    int pb = bid - 64;
    const int* src; int ne, ch; uint32_t* seg; int* cnts;
    if (pb < nbm)            { src = mask; ne = em; ch = pb;             seg = segM; cnts = counts; }
    else if (pb < nbm + nb1) { src = ei1;  ne = e1; ch = pb - nbm;       seg = seg1; cnts = counts + nbm * NB; }
    else                     { src = ei2;  ne = e2; ch = pb - nbm - nb1; seg = seg2; cnts = counts + (nbm + nb1) * NB; }
    int base = ch * CHUNK;
    int n = ne - base;
    if (n > CHUNK) n = CHUNK;

    for (int i = t; i < NB; i += 256) cur[i] = 0;
    __syncthreads();

    // pack pk = (d<<13)|s; bucket = d>>4 = pk>>17; direct store to segment
#pragma unroll
    for (int k = 0; k < 16; ++k) {
        int i = t + k * 256;
        if (i < n) {
            int s = src[base + i];
            int d = src[ne + base + i];
            uint32_t pk = ((uint32_t)d << 13) | (uint32_t)s;
            int b = pk >> 17;
            int off = atomicAdd(&cur[b], 1);
            if (off < SEGC) seg[(ch * NB + b) * SEGC + off] = pk;
        }
    }
    __syncthreads();
    for (int i = t; i < NB; i += 256) cnts[ch * NB + i] = min(cur[i], SEGC);
}

// ---- K2: per-bucket filter + register-slab A1/A2 ---------------------------
// bucket b owns target rows [16b,16b+16). z/y accumulate in registers
// (8 each/thread: rowgroup rg = t>>7 -> rows rg*8..rg*8+8, col c = t&127).
__global__ __launch_bounds__(256) void k2_fs(
    const uint32_t* __restrict__ segM, const uint32_t* __restrict__ seg1,
    const uint32_t* __restrict__ seg2, const int* __restrict__ counts,
    const float* __restrict__ x, const float* __restrict__ Mg,
    float* __restrict__ z, float* __restrict__ y, int* __restrict__ c2g,
    int nbm, int nb1, int nb2) {
    __shared__ uint32_t bmap[4096];     // 16 KB: bit (d&15)*8192 + s
    __shared__ uint32_t pass[PCAP], pass2[PCAP];
    __shared__ float xsh[2][DD], xdh[2][DD];
    __shared__ float red[2][2];
    __shared__ int pc, npd;

    int b = blockIdx.x;
    int t = threadIdx.x;
    int g = t >> 7;            // edge-slot / row-group
    int c = t & 127;
    float zreg[8] = {0.f,0.f,0.f,0.f,0.f,0.f,0.f,0.f};
    float yreg[8] = {0.f,0.f,0.f,0.f,0.f,0.f,0.f,0.f};

    const int* cntM  = counts;
    const int* cnt1c = counts + nbm * NB;
    const int* cnt2c = counts + (nbm + nb1) * NB;

    for (int i = t; i < 4096; i += 256) bmap[i] = 0;
    if (t == 0) pc = 0;
    __syncthreads();

    // build mask bitmap (duplicates harmless)
    int slotsM = nbm * SEGC;
    for (int i = t; i < slotsM; i += 256) {
        int ch = i >> 5, j = i & 31;
        if (j < cntM[ch * NB + b]) {
            uint32_t pk = segM[(ch * NB + b) * SEGC + j];
            uint32_t bi = pk & 0x1FFFFu;
            atomicOr(&bmap[bi >> 5], 1u << (bi & 31));
        }
    }
    __syncthreads();

    // ---- probe e1 -> candidates (dups ok) ----
    int slots1 = nb1 * SEGC;
    for (int i = t; i < slots1; i += 256) {
        int ch = i >> 5, j = i & 31;
        if (j < cnt1c[ch * NB + b]) {
            uint32_t pk = seg1[(ch * NB + b) * SEGC + j];
            uint32_t bi = pk & 0x1FFFFu;
            if (bmap[bi >> 5] & (1u << (bi & 31))) {
                int p = atomicAdd(&pc, 1);
                if (p < PCAP) pass[p] = pk;
            }
        }
    }
    __syncthreads();
    // dedup + compact (wave 0)
    {
        int np = min(pc, PCAP);
        if (t < 64) {
            bool keep = false; uint32_t v = 0;
            if (t < np) {
                v = pass[t]; keep = true;
                for (int j2 = 0; j2 < t; ++j2)
                    if (pass[j2] == v) { keep = false; break; }
            }
            unsigned long long mb = __ballot(keep);
            if (keep) pass2[__popcll(mb & ((1ull << t) - 1ull))] = v;
            if (t == 0) npd = (int)__popcll(mb);
        }
    }
    __syncthreads();
    int n1p = npd;

    // A1: zreg[row of d] += x[s], 2 edges per pass
    for (int p0 = 0; p0 < n1p; p0 += 2) {
        int e = p0 + g;
        if (e < n1p) xsh[g][c] = x[(pass2[e] & 8191) * DD + c];
        __syncthreads();
#pragma unroll
        for (int ee = 0; ee < 2; ++ee) {
            int ei = p0 + ee;
            if (ei < n1p) {
                uint32_t pk = pass2[ei];
                int d15 = (pk >> 13) & 15;
                if ((d15 >> 3) == g) {
                    float xv = xsh[ee][c];
                    int r0 = d15 & 7;
#pragma unroll
                    for (int r = 0; r < 8; ++r)
                        zreg[r] += (r == r0) ? xv : 0.f;
                }
            }
        }
        __syncthreads();
    }

    // ---- probe e2 ----
    if (t == 0) pc = 0;
    __syncthreads();
    int slots2 = nb2 * SEGC;
    for (int i = t; i < slots2; i += 256) {
        int ch = i >> 5, j = i & 31;
        if (j < cnt2c[ch * NB + b]) {
            uint32_t pk = seg2[(ch * NB + b) * SEGC + j];
            uint32_t bi = pk & 0x1FFFFu;
            if (bmap[bi >> 5] & (1u << (bi & 31))) {
                int p = atomicAdd(&pc, 1);
                if (p < PCAP) pass[p] = pk;
            }
        }
    }
    __syncthreads();
    {
        int np = min(pc, PCAP);
        if (t < 64) {
            bool keep = false; uint32_t v = 0;
            if (t < np) {
                v = pass[t]; keep = true;
                for (int j2 = 0; j2 < t; ++j2)
                    if (pass[j2] == v) { keep = false; break; }
            }
            unsigned long long mb = __ballot(keep);
            if (keep) pass2[__popcll(mb & ((1ull << t) - 1ull))] = v;
            if (t == 0) npd = (int)__popcll(mb);
        }
    }
    __syncthreads();
    int n2p = npd;
    if (t == 0 && n2p) atomicAdd(c2g, n2p);

    // A2: yreg[row of d] += (x[d] @ M @ x[s]) * x[s], 2 edges per pass
    for (int p0 = 0; p0 < n2p; p0 += 2) {
        int e = p0 + g;
        if (e < n2p) {
            uint32_t pk = pass2[e];
            int s = pk & 8191, d15 = (pk >> 13) & 15;
            xsh[g][c] = x[s * DD + c];
            xdh[g][c] = x[((b << 4) + d15) * DD + c];
        }
        __syncthreads();
        if (e < n2p) {
            float acc = 0.f;
#pragma unroll 8
            for (int a = 0; a < DD; ++a)
                acc += xdh[g][a] * Mg[a * DD + c];   // coalesced, L2-resident
            float part = acc * xsh[g][c];
            for (int off = 32; off; off >>= 1)
                part += __shfl_down(part, off, 64);
            if ((t & 63) == 0) red[g][(t >> 6) & 1] = part;
        }
        __syncthreads();
#pragma unroll
        for (int ee = 0; ee < 2; ++ee) {
            int ei = p0 + ee;
            if (ei < n2p) {
                float se = red[ee][0] + red[ee][1];
                uint32_t pk = pass2[ei];
                int d15 = (pk >> 13) & 15;
                if ((d15 >> 3) == g) {
                    float xv = xsh[ee][c];
                    int r0 = d15 & 7;
#pragma unroll
                    for (int r = 0; r < 8; ++r)
                        yreg[r] += (r == r0) ? se * xv : 0.f;
                }
            }
        }
        __syncthreads();
    }

    // coalesced writeout (complete rows; no pre-zero anywhere)
#pragma unroll
    for (int r = 0; r < 8; ++r) {
        int row = (b << 4) + g * 8 + r;
        z[row * DD + c] = zreg[r];
        y[row * DD + c] = yreg[r];
    }
}

// ---- K3: epilogue (R5-proven), x2 = y @ Wv^T fused via split-bf16 ----------
__global__ __launch_bounds__(256) void epilogue_mfma(
    const float* __restrict__ x, const float* __restrict__ z,
    const float* __restrict__ y, const float* __restrict__ Wv,
    const float* __restrict__ Wg0, const float* __restrict__ Wg1,
    const int* __restrict__ cnt2, float inv_np1, float coef_x,
    float* __restrict__ out) {
    int lane = threadIdx.x & 63;
    int wave = threadIdx.x >> 6;
    int i16  = lane & 15;
    int kg   = lane >> 4;
    int rowbase = blockIdx.x * 16;
    int colbase = wave * 32;

    f32x4 acc[2] = {}, acc2[2] = {};
#pragma unroll
    for (int kk = 0; kk < 8; ++kk) {
        const float* src = (kk < 4) ? x : z;
        const float* W   = (kk < 4) ? Wg0 : Wg1;
        int kofs = (kk & 3) * 32 + kg * 8;
        bf16x8 a  = ld_bf16x8(src + (rowbase + i16) * DD + kofs);
        bf16x8 b0 = ld_bf16x8(W + (colbase +      i16) * DD + kofs);
        bf16x8 b1 = ld_bf16x8(W + (colbase + 16 + i16) * DD + kofs);
        acc[0] = __builtin_amdgcn_mfma_f32_16x16x32_bf16(a, b0, acc[0], 0, 0, 0);
        acc[1] = __builtin_amdgcn_mfma_f32_16x16x32_bf16(a, b1, acc[1], 0, 0, 0);
    }
#pragma unroll
    for (int kk = 0; kk < 4; ++kk) {
        int kofs = kk * 32 + kg * 8;
        bf16x8 yh, yl, w0h, w0l, w1h, w1l;
        ld_split(y + (rowbase + i16) * DD + kofs, yh, yl);
        ld_split(Wv + (colbase +      i16) * DD + kofs, w0h, w0l);
        ld_split(Wv + (colbase + 16 + i16) * DD + kofs, w1h, w1l);
        acc2[0] = __builtin_amdgcn_mfma_f32_16x16x32_bf16(yh, w0h, acc2[0], 0, 0, 0);
        acc2[0] = __builtin_amdgcn_mfma_f32_16x16x32_bf16(yh, w0l, acc2[0], 0, 0, 0);
        acc2[0] = __builtin_amdgcn_mfma_f32_16x16x32_bf16(yl, w0h, acc2[0], 0, 0, 0);
        acc2[1] = __builtin_amdgcn_mfma_f32_16x16x32_bf16(yh, w1h, acc2[1], 0, 0, 0);
        acc2[1] = __builtin_amdgcn_mfma_f32_16x16x32_bf16(yh, w1l, acc2[1], 0, 0, 0);
        acc2[1] = __builtin_amdgcn_mfma_f32_16x16x32_bf16(yl, w1h, acc2[1], 0, 0, 0);
    }
    float scale2 = (float)NN / (float)(*cnt2);
#pragma unroll
    for (int t = 0; t < 2; ++t)
#pragma unroll
        for (int r = 0; r < 4; ++r) {
            int row = rowbase + kg * 4 + r;
            int col = colbase + t * 16 + i16;
            float xv = x[row * DD + col];
            out[row * DD + col] = acc[t][r] * inv_np1 + coef_x * xv
                                - acc2[t][r] * scale2;
        }
}

// ---- host ------------------------------------------------------------------

extern "C" void kernel_launch(void* const* d_in, const int* in_sizes, int n_in,
                              void* d_out, int out_size, void* d_ws, size_t ws_size,
                              hipStream_t stream) {
    const float* x   = (const float*)d_in[0];
    const int* ei1   = (const int*)d_in[1];
    const int* ei2   = (const int*)d_in[2];
    const int* mask  = (const int*)d_in[3];
    const float* Wg0 = (const float*)d_in[4];
    const float* Wg1 = (const float*)d_in[5];
    const float* Wq  = (const float*)d_in[6];
    const float* Wk  = (const float*)d_in[7];
    const float* Wv  = (const float*)d_in[8];
    float* out = (float*)d_out;

    int e1 = in_sizes[1] / 2;
    int e2 = in_sizes[2] / 2;
    int em = in_sizes[3] / 2;
    float np1 = (float)em / (float)NN;
    float inv1 = 1.0f / np1;
    float coefx = (np1 - 1.0f) * inv1;

    int nbm = (em + CHUNK - 1) / CHUNK;   // 128
    int nb1 = (e1 + CHUNK - 1) / CHUNK;   // 64
    int nb2 = (e2 + CHUNK - 1) / CHUNK;   // 64
    int npart = nbm + nb1 + nb2;          // 256

    char* ws = (char*)d_ws;
    const size_t O_M    = 0;                                        // 64 KB
    const size_t O_C2   = 65536;
    const size_t O_CNTS = O_C2 + 64;                                // 512 KB
    const size_t O_SEGM = O_CNTS + (size_t)npart * NB * 4;
    const size_t O_SEG1 = O_SEGM + (size_t)nbm * NB * SEGC * 4;     // +8 MB
    const size_t O_SEG2 = O_SEG1 + (size_t)nb1 * NB * SEGC * 4;     // +4 MB
    const size_t O_Z    = O_SEG2 + (size_t)nb2 * NB * SEGC * 4;     // +4 MB
    const size_t O_Y    = O_Z + (size_t)NN * DD * 4;                // +4 MB
    // end ~ 24.6 MB

    float*    M     = (float*)(ws + O_M);
    int*      c2    = (int*)(ws + O_C2);
    int*      cnts  = (int*)(ws + O_CNTS);
    uint32_t* segM  = (uint32_t*)(ws + O_SEGM);
    uint32_t* seg1  = (uint32_t*)(ws + O_SEG1);
    uint32_t* seg2  = (uint32_t*)(ws + O_SEG2);
    float*    z     = (float*)(ws + O_Z);
    float*    y     = (float*)(ws + O_Y);

    k1_prep<<<64 + npart, 256, 0, stream>>>(
        ei1, e1, ei2, e2, mask, em, Wq, Wk,
        M, c2, segM, seg1, seg2, cnts, nbm, nb1, nb2);
    k2_fs<<<NB, 256, 0, stream>>>(
        segM, seg1, seg2, cnts, x, M, z, y, c2, nbm, nb1, nb2);
    epilogue_mfma<<<NN / 16, 256, 0, stream>>>(
        x, z, y, Wv, Wg0, Wg1, c2, inv1, coefx, out);
}

// Round 10
// 57.971 us; speedup vs baseline: 1.3884x; 1.3884x over previous
//
#include <hip/hip_runtime.h>
#include <hip/hip_bf16.h>
#include <stdint.h>

#define NN 8192
#define DD 128

#define NBUCK 256          // bucket = d >> 5 (32 target rows per bucket)
#define CHUNK 4096         // edges per partition chunk
#define SEGC 48            // per-(bucket,chunk) segment capacity (mean 16)
#define EPT 16             // CHUNK / 256
#define PCAP 128           // per-bucket passer capacity (mean ~16)

typedef __bf16 bf16x8 __attribute__((ext_vector_type(8)));
typedef float  f32x4  __attribute__((ext_vector_type(4)));

__device__ inline bf16x8 ld_bf16x8(const float* p) {
    float4 u0 = *(const float4*)p;
    float4 u1 = *(const float4*)(p + 4);
    bf16x8 r;
    r[0] = (__bf16)u0.x; r[1] = (__bf16)u0.y; r[2] = (__bf16)u0.z; r[3] = (__bf16)u0.w;
    r[4] = (__bf16)u1.x; r[5] = (__bf16)u1.y; r[6] = (__bf16)u1.z; r[7] = (__bf16)u1.w;
    return r;
}

// split fp32x8 into bf16 hi + lo residual (3-term MFMA ~ fp32 accuracy)
__device__ inline void ld_split(const float* p, bf16x8& h, bf16x8& l) {
    float4 u0 = *(const float4*)p;
    float4 u1 = *(const float4*)(p + 4);
    float v[8] = {u0.x, u0.y, u0.z, u0.w, u1.x, u1.y, u1.z, u1.w};
#pragma unroll
    for (int i = 0; i < 8; ++i) {
        __bf16 hh = (__bf16)v[i];
        h[i] = hh;
        l[i] = (__bf16)(v[i] - (float)hh);
    }
}

// ---- K1: M-gemm(fp32) + d-keyed radix partition, BUCKET-MAJOR layout -------
// blocks: [0,64) M-gemm | [64,64+npart) partition | [64+npart,+128) zero z|y
__global__ __launch_bounds__(256) void k1_prep(
    const int* __restrict__ ei1, int e1,
    const int* __restrict__ ei2, int e2,
    const int* __restrict__ mask, int em,
    const float* __restrict__ Wq, const float* __restrict__ Wk,
    float* __restrict__ M,
    float4* __restrict__ zy, int* __restrict__ c2g,
    uint32_t* __restrict__ segM, uint32_t* __restrict__ seg1,
    uint32_t* __restrict__ seg2, int* __restrict__ counts,
    int nbm, int nb1, int nb2) {
    __shared__ int cnt[NBUCK];
    __shared__ int sc[2][NBUCK];
    __shared__ int startS[NBUCK];
    __shared__ int cur[NBUCK];
    __shared__ uint32_t stage[CHUNK];

    int bid = blockIdx.x;
    int t = threadIdx.x;
    int npart = nbm + nb1 + nb2;

    if (bid < 64) {
        if (bid == 0 && t == 0) *c2g = 0;
        int c = bid * 2 + (t >> 7);
        int e = t & 127;
        float acc = 0.f;
#pragma unroll 8
        for (int a = 0; a < DD; ++a)
            acc += Wq[a * DD + c] * Wk[a * DD + e];
        M[c * DD + e] = acc;
        return;
    }
    if (bid < 64 + npart) {
        int pb = bid - 64;
        const int* src; int ne, ch, NC; uint32_t* seg; int* cnts;
        if (pb < nbm)            { src = mask; ne = em; ch = pb;             NC = nbm; seg = segM; cnts = counts; }
        else if (pb < nbm + nb1) { src = ei1;  ne = e1; ch = pb - nbm;       NC = nb1; seg = seg1; cnts = counts + NBUCK * nbm; }
        else                     { src = ei2;  ne = e2; ch = pb - nbm - nb1; NC = nb2; seg = seg2; cnts = counts + NBUCK * (nbm + nb1); }
        int base = ch * CHUNK;
        int n = ne - base;
        if (n > CHUNK) n = CHUNK;

        cnt[t] = 0;
        __syncthreads();

        // pack pk = (d << 13) | s  -> bucket = d>>5 = pk>>18; bit = pk & 0x3FFFF
        uint32_t pk[EPT];
#pragma unroll
        for (int k = 0; k < EPT; ++k) {
            int i = t + k * 256;
            if (i < n) {
                int s = src[base + i];
                int d = src[ne + base + i];
                pk[k] = ((uint32_t)d << 13) | (uint32_t)s;
                atomicAdd(&cnt[pk[k] >> 18], 1);
            } else pk[k] = 0xFFFFFFFFu;
        }
        __syncthreads();

        // inclusive scan of cnt
        sc[0][t] = cnt[t];
        __syncthreads();
        int sb = 0;
        for (int off = 1; off < NBUCK; off <<= 1) {
            int d2 = sb ^ 1;
            sc[d2][t] = (t >= off) ? sc[sb][t] + sc[sb][t - off] : sc[sb][t];
            sb = d2;
            __syncthreads();
        }
        int startv = (t == 0) ? 0 : sc[sb][t - 1];
        startS[t] = startv;
        cur[t] = startv;
        cnts[t * NC + ch] = min(cnt[t], SEGC);      // bucket-major counts
        __syncthreads();

        // bucket-sort into LDS
#pragma unroll
        for (int k = 0; k < EPT; ++k) {
            if (pk[k] != 0xFFFFFFFFu) {
                int b = pk[k] >> 18;
                int p = atomicAdd(&cur[b], 1);
                stage[p] = pk[k];
            }
        }
        __syncthreads();

        // flush: per-bucket contiguous runs into BUCKET-MAJOR segments
        for (int i = t; i < n; i += 256) {
            uint32_t v = stage[i];
            int b = v >> 18;
            int off = i - startS[b];
            if (off < SEGC) seg[((size_t)b * NC + ch) * SEGC + off] = v;
        }
        return;
    }
    // zero blocks: z + y (8 MB = 524288 float4)
    int zb = bid - (64 + npart);
    int idx = zb * 256 + t;
    int stride = 128 * 256;
    for (int i = idx; i < 524288; i += stride)
        zy[i] = make_float4(0.f, 0.f, 0.f, 0.f);
}

// ---- K2: per-bucket filter + A1/A2 scatter (streaming bucket-major reads) --
__global__ __launch_bounds__(1024) void k2_fs(
    const uint32_t* __restrict__ segM, const uint32_t* __restrict__ seg1,
    const uint32_t* __restrict__ seg2, const int* __restrict__ counts,
    const float* __restrict__ x, const float* __restrict__ Mg,
    float* __restrict__ z, float* __restrict__ y, int* __restrict__ c2g,
    int nbm, int nb1, int nb2) {
    __shared__ uint32_t bmap[8192];     // 32 KB: bit (d&31)*8192 + s
    __shared__ uint32_t seen[8192];     // 32 KB dedup
    __shared__ uint32_t pass[PCAP];
    __shared__ float xs[8][DD], xd[8][DD], red[8][2];
    __shared__ int csh[256];            // per-bucket counts (nbm+nb1+nb2)
    __shared__ int pc;

    int b = blockIdx.x;
    int t = threadIdx.x;

    // one coalesced count stage: bucket-major -> contiguous
    if (t < nbm)                  csh[t] = counts[b * nbm + t];
    else if (t < nbm + nb1)       csh[t] = counts[NBUCK * nbm + b * nb1 + (t - nbm)];
    else if (t < nbm + nb1 + nb2) csh[t] = counts[NBUCK * (nbm + nb1) + b * nb2 + (t - nbm - nb1)];
    for (int i = t; i < 8192; i += 1024) { bmap[i] = 0; seen[i] = 0; }
    if (t == 0) pc = 0;
    __syncthreads();

    // build mask bitmap: contiguous stream of this bucket's mask segments
    int slotsM = nbm * SEGC;
    for (int i = t; i < slotsM; i += 1024) {
        int ch = i / SEGC, j = i - ch * SEGC;
        if (j < csh[ch]) {
            uint32_t pk = segM[((size_t)b * nbm + ch) * SEGC + j];
            uint32_t bi = pk & 0x3FFFFu;
            atomicOr(&bmap[bi >> 5], 1u << (bi & 31));
        }
    }
    __syncthreads();

    // probe e1; dedup via seen
    int slots1 = nb1 * SEGC;
    for (int i = t; i < slots1; i += 1024) {
        int ch = i / SEGC, j = i - ch * SEGC;
        if (j < csh[nbm + ch]) {
            uint32_t pk = seg1[((size_t)b * nb1 + ch) * SEGC + j];
            uint32_t bi = pk & 0x3FFFFu;
            uint32_t m = 1u << (bi & 31);
            if (bmap[bi >> 5] & m) {
                uint32_t old = atomicOr(&seen[bi >> 5], m);
                if (!(old & m)) {
                    int pp = atomicAdd(&pc, 1);
                    if (pp < PCAP) pass[pp] = pk;
                }
            }
        }
    }
    __syncthreads();
    int np = min(pc, PCAP);
    int g = t >> 7, c = t & 127;

    // A1: z[d] += x[s], 8 edges in parallel
    for (int p0 = 0; p0 < np; p0 += 8) {
        int e = p0 + g;
        if (e < np) {
            uint32_t pk = pass[e];
            int s = pk & 8191, d = pk >> 13;
            atomicAdd(&z[d * DD + c], x[s * DD + c]);
        }
    }
    __syncthreads();
    if (t == 0) pc = 0;
    for (int i = t; i < 8192; i += 1024) seen[i] = 0;
    __syncthreads();

    // probe e2
    int slots2 = nb2 * SEGC;
    for (int i = t; i < slots2; i += 1024) {
        int ch = i / SEGC, j = i - ch * SEGC;
        if (j < csh[nbm + nb1 + ch]) {
            uint32_t pk = seg2[((size_t)b * nb2 + ch) * SEGC + j];
            uint32_t bi = pk & 0x3FFFFu;
            uint32_t m = 1u << (bi & 31);
            if (bmap[bi >> 5] & m) {
                uint32_t old = atomicOr(&seen[bi >> 5], m);
                if (!(old & m)) {
                    int pp = atomicAdd(&pc, 1);
                    if (pp < PCAP) pass[pp] = pk;
                }
            }
        }
    }
    __syncthreads();
    np = min(pc, PCAP);
    if (t == 0 && np) atomicAdd(c2g, np);

    // A2: y[d] += (x[d] @ M @ x[s]) * x[s]
    for (int p0 = 0; p0 < np; p0 += 8) {
        __syncthreads();
        int e = p0 + g;
        bool val = e < np;
        uint32_t pk = val ? pass[e] : 0;
        int s = pk & 8191;
        int d = pk >> 13;
        if (val) {
            xs[g][c] = x[s * DD + c];
            xd[g][c] = x[d * DD + c];
        }
        __syncthreads();
        if (val) {
            float acc = 0.f;
#pragma unroll 8
            for (int a = 0; a < DD; ++a)
                acc += xd[g][a] * Mg[a * DD + c];   // coalesced, L2-resident
            float part = acc * xs[g][c];
            for (int off2 = 32; off2; off2 >>= 1)
                part += __shfl_down(part, off2, 64);
            if ((c & 63) == 0) red[g][c >> 6] = part;
        }
        __syncthreads();
        if (val) {
            float se = red[g][0] + red[g][1];
            atomicAdd(&y[d * DD + c], se * xs[g][c]);
        }
    }
}

// ---- K3: epilogue (R5-proven), x2 = y @ Wv^T fused via split-bf16 ----------
__global__ __launch_bounds__(256) void epilogue_mfma(
    const float* __restrict__ x, const float* __restrict__ z,
    const float* __restrict__ y, const float* __restrict__ Wv,
    const float* __restrict__ Wg0, const float* __restrict__ Wg1,
    const int* __restrict__ cnt2, float inv_np1, float coef_x,
    float* __restrict__ out) {
    int lane = threadIdx.x & 63;
    int wave = threadIdx.x >> 6;
    int i16  = lane & 15;
    int kg   = lane >> 4;
    int rowbase = blockIdx.x * 16;
    int colbase = wave * 32;

    f32x4 acc[2] = {}, acc2[2] = {};
#pragma unroll
    for (int kk = 0; kk < 8; ++kk) {
        const float* src = (kk < 4) ? x : z;
        const float* W   = (kk < 4) ? Wg0 : Wg1;
        int kofs = (kk & 3) * 32 + kg * 8;
        bf16x8 a  = ld_bf16x8(src + (rowbase + i16) * DD + kofs);
        bf16x8 b0 = ld_bf16x8(W + (colbase +      i16) * DD + kofs);
        bf16x8 b1 = ld_bf16x8(W + (colbase + 16 + i16) * DD + kofs);
        acc[0] = __builtin_amdgcn_mfma_f32_16x16x32_bf16(a, b0, acc[0], 0, 0, 0);
        acc[1] = __builtin_amdgcn_mfma_f32_16x16x32_bf16(a, b1, acc[1], 0, 0, 0);
    }
#pragma unroll
    for (int kk = 0; kk < 4; ++kk) {
        int kofs = kk * 32 + kg * 8;
        bf16x8 yh, yl, w0h, w0l, w1h, w1l;
        ld_split(y + (rowbase + i16) * DD + kofs, yh, yl);
        ld_split(Wv + (colbase +      i16) * DD + kofs, w0h, w0l);
        ld_split(Wv + (colbase + 16 + i16) * DD + kofs, w1h, w1l);
        acc2[0] = __builtin_amdgcn_mfma_f32_16x16x32_bf16(yh, w0h, acc2[0], 0, 0, 0);
        acc2[0] = __builtin_amdgcn_mfma_f32_16x16x32_bf16(yh, w0l, acc2[0], 0, 0, 0);
        acc2[0] = __builtin_amdgcn_mfma_f32_16x16x32_bf16(yl, w0h, acc2[0], 0, 0, 0);
        acc2[1] = __builtin_amdgcn_mfma_f32_16x16x32_bf16(yh, w1h, acc2[1], 0, 0, 0);
        acc2[1] = __builtin_amdgcn_mfma_f32_16x16x32_bf16(yh, w1l, acc2[1], 0, 0, 0);
        acc2[1] = __builtin_amdgcn_mfma_f32_16x16x32_bf16(yl, w1h, acc2[1], 0, 0, 0);
    }
    float scale2 = (float)NN / (float)(*cnt2);
#pragma unroll
    for (int t = 0; t < 2; ++t)
#pragma unroll
        for (int r = 0; r < 4; ++r) {
            int row = rowbase + kg * 4 + r;
            int col = colbase + t * 16 + i16;
            float xv = x[row * DD + col];
            out[row * DD + col] = acc[t][r] * inv_np1 + coef_x * xv
                                - acc2[t][r] * scale2;
        }
}

// ---- host ------------------------------------------------------------------

extern "C" void kernel_launch(void* const* d_in, const int* in_sizes, int n_in,
                              void* d_out, int out_size, void* d_ws, size_t ws_size,
                              hipStream_t stream) {
    const float* x   = (const float*)d_in[0];
    const int* ei1   = (const int*)d_in[1];
    const int* ei2   = (const int*)d_in[2];
    const int* mask  = (const int*)d_in[3];
    const float* Wg0 = (const float*)d_in[4];
    const float* Wg1 = (const float*)d_in[5];
    const float* Wq  = (const float*)d_in[6];
    const float* Wk  = (const float*)d_in[7];
    const float* Wv  = (const float*)d_in[8];
    float* out = (float*)d_out;

    int e1 = in_sizes[1] / 2;
    int e2 = in_sizes[2] / 2;
    int em = in_sizes[3] / 2;
    float np1 = (float)em / (float)NN;
    float inv1 = 1.0f / np1;
    float coefx = (np1 - 1.0f) * inv1;

    int nbm = (em + CHUNK - 1) / CHUNK;   // 128
    int nb1 = (e1 + CHUNK - 1) / CHUNK;   // 64
    int nb2 = (e2 + CHUNK - 1) / CHUNK;   // 64
    int npart = nbm + nb1 + nb2;          // 256

    char* ws = (char*)d_ws;
    const size_t O_M    = 0;                                          // 64 KB
    const size_t O_C2   = 65536;
    const size_t O_CNTS = O_C2 + 64;                                  // 256 KB
    const size_t O_SEGM = O_CNTS + (size_t)NBUCK * npart * 4;
    const size_t O_SEG1 = O_SEGM + (size_t)NBUCK * nbm * SEGC * 4;    // +6.3 MB
    const size_t O_SEG2 = O_SEG1 + (size_t)NBUCK * nb1 * SEGC * 4;    // +3.1 MB
    const size_t O_Z    = O_SEG2 + (size_t)NBUCK * nb2 * SEGC * 4;    // +3.1 MB
    const size_t O_Y    = O_Z + (size_t)NN * DD * 4;                  // +4 MB
    // end ~ 20.9 MB

    float*    M     = (float*)(ws + O_M);
    int*      c2    = (int*)(ws + O_C2);
    int*      cnts  = (int*)(ws + O_CNTS);
    uint32_t* segM  = (uint32_t*)(ws + O_SEGM);
    uint32_t* seg1  = (uint32_t*)(ws + O_SEG1);
    uint32_t* seg2  = (uint32_t*)(ws + O_SEG2);
    float*    z     = (float*)(ws + O_Z);
    float*    y     = (float*)(ws + O_Y);

    k1_prep<<<64 + npart + 128, 256, 0, stream>>>(
        ei1, e1, ei2, e2, mask, em, Wq, Wk,
        M, (float4*)z, c2, segM, seg1, seg2, cnts, nbm, nb1, nb2);
    k2_fs<<<NBUCK, 1024, 0, stream>>>(
        segM, seg1, seg2, cnts, x, M, z, y, c2, nbm, nb1, nb2);
    epilogue_mfma<<<NN / 16, 256, 0, stream>>>(
        x, z, y, Wv, Wg0, Wg1, c2, inv1, coefx, out);
}